// Round 3
// baseline (177.912 us; speedup 1.0000x reference)
//
#include <hip/hip_runtime.h>
#include <hip/hip_bf16.h>
#include <stdint.h>

// LePEAttention via MFMA. B=4, C=64, H=W=128, heads=8, hd=8, window=128x2 (256 toks).
// Block = (b, wi, half): 512 blocks, 256 thr = 4 waves = 4 heads.
// Per wave: 16 M-strips (16 queries) x [4 chunks x (4 QK mfma -> exp -> P to LDS -> 2 PV mfma)].
// mfma_f32_16x16x32_bf16; d=8 padded to K=32 (lanes>=16 hold zero A/B frags).

typedef __attribute__((ext_vector_type(8))) short bf16x8;
typedef __attribute__((ext_vector_type(4))) float f32x4;

static __device__ __forceinline__ uint32_t pk2(float x, float y) {
    union { __hip_bfloat162 h2; uint32_t u; } c;
    c.h2 = __float22bfloat162_rn(make_float2(x, y));
    return c.u;
}

__global__ __launch_bounds__(256, 2)
void lepe_attn(const float* __restrict__ temp,
               const float* __restrict__ conv_w,
               const float* __restrict__ conv_b,
               float* __restrict__ out)
{
    // LDS: q region 20480B ([256][40] bf16; later per-wave P buffers 16x72 bf16),
    //      k region 20480B ([256][40] bf16, stride 80B -> conflict-free b128 frag reads),
    //      v region 16896B ([32 ch][264 toks] bf16, stride 528B).
    __shared__ __align__(16) char smem[57856];
    char* q_b = smem;
    char* k_b = smem + 20480;
    char* v_b = smem + 40960;

    const int tid  = threadIdx.x;
    const int wave = tid >> 6, lane = tid & 63;
    const int lr = lane & 15, g = lane >> 4;
    const int dd = lane & 7;

    // XCD swizzle: XCD = bid%8 owns wi in [8x, 8x+8) -> 16 consecutive w = one 64B line.
    const int bid = blockIdx.x;
    const int x = bid & 7, y = bid >> 3;
    const int wi = x * 8 + (y & 7);
    const int b  = (y >> 3) & 3;
    const int hf = y >> 5;
    const int c0 = hf * 32;

    const size_t cstr = 16384, sstr = 64 * cstr;
    const float* qg = temp + (size_t)b * 3 * sstr;
    const float* kg = qg + sstr;
    const float* vg = qg + 2 * sstr;

    const int cg = tid & 31, hh0 = (tid >> 5) & 7;
    const float qs = 0.35355339059327373f * 1.4426950408889634f; // hd^-0.5 * log2e

    // ---- stage Q (scaled) and K as bf16, tok-major stride 40 bf16 ----
    {
        const float* qp = qg + (size_t)(c0 + cg) * cstr + wi * 2;
        const float* kp = kg + (size_t)(c0 + cg) * cstr + wi * 2;
        #pragma unroll
        for (int i = 0; i < 16; ++i) {
            int h = i * 8 + hh0;
            float2 f = *(const float2*)(qp + h * 128);
            uint32_t pq = pk2(f.x * qs, f.y * qs);
            *(uint16_t*)(q_b + (2*h)   * 80 + cg * 2) = (uint16_t)pq;
            *(uint16_t*)(q_b + (2*h+1) * 80 + cg * 2) = (uint16_t)(pq >> 16);
            float2 fk = *(const float2*)(kp + h * 128);
            uint32_t pkv = pk2(fk.x, fk.y);
            *(uint16_t*)(k_b + (2*h)   * 80 + cg * 2) = (uint16_t)pkv;
            *(uint16_t*)(k_b + (2*h+1) * 80 + cg * 2) = (uint16_t)(pkv >> 16);
        }
        // ---- stage V as [ch][tok] bf16 (B-frag layout), b128 writes ----
        const float* vp = vg + (size_t)(c0 + cg) * cstr + wi * 2;
        #pragma unroll
        for (int j = 0; j < 4; ++j) {
            uint32_t w0[4];
            #pragma unroll
            for (int i2 = 0; i2 < 4; ++i2) {
                int h = hh0 * 16 + j * 4 + i2;
                float2 f = *(const float2*)(vp + h * 128);
                w0[i2] = pk2(f.x, f.y);
            }
            *(uint4*)(v_b + cg * 528 + hh0 * 64 + j * 16) = make_uint4(w0[0], w0[1], w0[2], w0[3]);
        }
    }

    // ---- conv weights/bias -> regs (per-lane channel c0 + wave*8 + dd) ----
    const int cglob = c0 + wave * 8 + dd;
    float cwr[9];
    #pragma unroll
    for (int t = 0; t < 9; ++t) cwr[t] = conv_w[cglob * 9 + t];
    const float cbr = conv_b[cglob];

    __syncthreads();

    // ---- Q A-frags for all 16 strips -> registers (lanes>=16 zero) ----
    const uint4 z4 = make_uint4(0, 0, 0, 0);
    uint4 qf[16];
    #pragma unroll
    for (int s = 0; s < 16; ++s) {
        uint4 t = *(const uint4*)(q_b + (s * 16 + lr) * 80 + wave * 16);
        qf[s] = (lane < 16) ? t : z4;
    }
    __syncthreads();   // q region now reusable as P buffers

    char* p_b = q_b + wave * 2304;   // wave-private 16 rows x 144B (72 bf16)

    const size_t obase = (size_t)b * 16384 * 64 + (size_t)(wi * 2) * 64 + c0 + wave * 8 + dd;
    const f32x4 zf = {0.f, 0.f, 0.f, 0.f};

    #pragma unroll 1
    for (int s = 0; s < 16; ++s) {
        f32x4 o = zf;
        float rs0 = 0.f, rs1 = 0.f, rs2 = 0.f, rs3 = 0.f;
        union { uint4 u; bf16x8 h; } qa; qa.u = qf[s];

        #pragma unroll
        for (int c4 = 0; c4 < 4; ++c4) {
            // 4 QK tiles (keys c4*64 .. +63)
            f32x4 sc[4];
            #pragma unroll
            for (int t = 0; t < 4; ++t) {
                int n0 = c4 * 64 + t * 16;
                uint4 kb = *(const uint4*)(k_b + (n0 + lr) * 80 + wave * 16);
                union { uint4 u; bf16x8 h; } kf; kf.u = (lane < 16) ? kb : z4;
                sc[t] = __builtin_amdgcn_mfma_f32_16x16x32_bf16(qa.h, kf.h, zf, 0, 0, 0);
            }
            // exp2 (scale*log2e folded into Q), rowsum, P -> LDS (bf16)
            #pragma unroll
            for (int t = 0; t < 4; ++t) {
                float e0 = __builtin_amdgcn_exp2f(sc[t][0]);
                float e1 = __builtin_amdgcn_exp2f(sc[t][1]);
                float e2 = __builtin_amdgcn_exp2f(sc[t][2]);
                float e3 = __builtin_amdgcn_exp2f(sc[t][3]);
                rs0 += e0; rs1 += e1; rs2 += e2; rs3 += e3;
                uint32_t p01 = pk2(e0, e1), p23 = pk2(e2, e3);
                char* pb = p_b + (t * 16 + lr) * 2;
                *(uint16_t*)(pb + (4*g + 0) * 144) = (uint16_t)p01;
                *(uint16_t*)(pb + (4*g + 1) * 144) = (uint16_t)(p01 >> 16);
                *(uint16_t*)(pb + (4*g + 2) * 144) = (uint16_t)p23;
                *(uint16_t*)(pb + (4*g + 3) * 144) = (uint16_t)(p23 >> 16);
            }
            // 2 PV mfma: A = P(16 x 64 chunk), B = V[key][d] (cols>=8 zero)
            #pragma unroll
            for (int kk = 0; kk < 2; ++kk) {
                uint4 pa = *(const uint4*)(p_b + lr * 144 + kk * 64 + g * 16);
                uint4 vb = *(const uint4*)(v_b + (wave * 8 + dd) * 528 + c4 * 128 + kk * 64 + g * 16);
                union { uint4 u; bf16x8 h; } paf, vbf;
                paf.u = pa;
                vbf.u = (lr < 8) ? vb : z4;
                o = __builtin_amdgcn_mfma_f32_16x16x32_bf16(paf.h, vbf.h, o, 0, 0, 0);
            }
        }
        // rowsum across the 16-lane col group
        #pragma unroll
        for (int m = 1; m < 16; m <<= 1) {
            rs0 += __shfl_xor(rs0, m);
            rs1 += __shfl_xor(rs1, m);
            rs2 += __shfl_xor(rs2, m);
            rs3 += __shfl_xor(rs3, m);
        }
        if (lr < 8) {
            // LePE conv taps: toks 16s+4g-2 .. +5, this lane's channel, zero outside window
            float tv[8];
            const int base_tok = s * 16 + 4 * g - 2;
            #pragma unroll
            for (int t = 0; t < 8; ++t) {
                int tok = base_tok + t;
                int tc = tok < 0 ? 0 : (tok > 255 ? 255 : tok);
                union { uint16_t u; __hip_bfloat16 h2; } lv;
                lv.u = *(const uint16_t*)(v_b + (wave * 8 + dd) * 528 + tc * 2);
                float val = __bfloat162float(lv.h2);
                tv[t] = (tok == tc) ? val : 0.f;
            }
            float rsv[4] = {rs0, rs1, rs2, rs3};
            #pragma unroll
            for (int r = 0; r < 4; ++r) {
                int w01 = r & 1;
                float rp = cbr;
                #pragma unroll
                for (int dy = 0; dy < 3; ++dy) {
                    #pragma unroll
                    for (int wp = 0; wp < 2; ++wp)
                        rp = fmaf(cwr[dy * 3 + (wp + 1 - w01)], tv[2 * (r >> 1) + 2 * dy + wp], rp);
                }
                int tok = s * 16 + 4 * g + r;
                out[obase + (size_t)(tok >> 1) * 8192 + (size_t)(tok & 1) * 64] = o[r] / rsv[r] + rp;
            }
        }
    }
}

extern "C" void kernel_launch(void* const* d_in, const int* in_sizes, int n_in,
                              void* d_out, int out_size, void* d_ws, size_t ws_size,
                              hipStream_t stream) {
    const float* temp = (const float*)d_in[0];
    const float* cw   = (const float*)d_in[1];
    const float* cb   = (const float*)d_in[2];
    float* o = (float*)d_out;
    (void)in_sizes; (void)n_in; (void)out_size; (void)d_ws; (void)ws_size;
    lepe_attn<<<dim3(512), dim3(256), 0, stream>>>(temp, cw, cb, o);
}